// Round 1
// baseline (1248.008 us; speedup 1.0000x reference)
//
#include <hip/hip_runtime.h>

typedef _Float16 half8 __attribute__((ext_vector_type(8)));
typedef float f32x4 __attribute__((ext_vector_type(4)));

#define MFMA16(a, b, c) __builtin_amdgcn_mfma_f32_16x16x32_f16(a, b, c, 0, 0, 0)

// ---------------------------------------------------------------- init out = b_out
__global__ void init_out_kernel(const float* __restrict__ bout, float* __restrict__ out) {
    int i = blockIdx.x * 256 + threadIdx.x;   // 524288 total
    out[i] = bout[i & 63];
}

// ---------------------------------------------------------------- qk projection
// qk = x @ W_qk.T ; q scaled by 0.125 ; split fp32 -> f16 hi + f16 lo.
// layouts: q_hi[b][h][n][d] etc. Each thread owns one output column o (W row in regs),
// iterates 64 x-rows staged in LDS (broadcast reads). 512 blocks -> 2 blocks/CU.
__global__ __launch_bounds__(256) void qk_proj_kernel(
    const float* __restrict__ x, const float* __restrict__ Wqk,
    _Float16* __restrict__ qhi, _Float16* __restrict__ qlo,
    _Float16* __restrict__ khi, _Float16* __restrict__ klo)
{
    __shared__ float4 xs[64][16];
    int t = threadIdx.x;
    int oc = blockIdx.x & 3;          // o-chunk: 4 * 256 = 1024 outputs
    int rowblk = blockIdx.x >> 2;     // 128 row-blocks of 64 rows
    int row0 = rowblk * 64;
    int o = oc * 256 + t;

    float4 wr[16];
    const float4* wp = (const float4*)(Wqk + o * 64);
#pragma unroll
    for (int j = 0; j < 16; ++j) wr[j] = wp[j];

    const float4* xsrc = (const float4*)(x + (size_t)row0 * 64);
#pragma unroll
    for (int i = 0; i < 4; ++i) {
        int idx = t + i * 256;        // 0..1023
        xs[idx >> 4][idx & 15] = xsrc[idx];
    }
    __syncthreads();

    bool isq = o < 512;
    int oo = isq ? o : o - 512;
    int h = oo >> 6, d = oo & 63;
    float scl = isq ? 0.125f : 1.0f;  // fold dots scale into q (exact, pow2)
    _Float16* hp = isq ? qhi : khi;
    _Float16* lp = isq ? qlo : klo;

    for (int r = 0; r < 64; ++r) {
        float acc = 0.f;
#pragma unroll
        for (int j = 0; j < 16; ++j) {
            float4 xv = xs[r][j];
            float4 wv = wr[j];
            acc += xv.x * wv.x + xv.y * wv.y + xv.z * wv.z + xv.w * wv.w;
        }
        float val = acc * scl;
        _Float16 hi = (_Float16)val;
        _Float16 lo = (_Float16)(val - (float)hi);
        int row = row0 + r;
        int b = row >> 11, n = row & 2047;
        size_t idx = ((size_t)((b * 8 + h) * 2048 + n) << 6) + d;
        hp[idx] = hi;
        lp[idx] = lo;
    }
}

// ---------------------------------------------------------------- conv value chain
// x(64) -> conv1(2ch,25tap) -> h1(2,40) -> conv2(4ch,2in,10tap) -> v(124), pad to 128.
// store transposed: vt[b][c][n]  (c-major rows of length 2048), f16.
__global__ __launch_bounds__(256) void conv_v_kernel(
    const float* __restrict__ x,
    const float* __restrict__ w1, const float* __restrict__ b1,
    const float* __restrict__ w2, const float* __restrict__ b2,
    _Float16* __restrict__ vt)
{
    __shared__ float xs[16][64];
    __shared__ float h1[16][80];          // [row][ci*40 + t]
    __shared__ float cw1[50], cb1[2], cw2[80], cb2[4];
    int t = threadIdx.x;
    int row0 = blockIdx.x * 16;

    ((float4*)&xs[0][0])[t] = ((const float4*)(x + (size_t)row0 * 64))[t];
    if (t < 50) cw1[t] = w1[t];
    else if (t < 52) cb1[t - 50] = b1[t - 50];
    else if (t < 132) cw2[t - 52] = w2[t - 52];
    else if (t < 136) cb2[t - 132] = b2[t - 132];
    __syncthreads();

    for (int it = t; it < 1280; it += 256) {      // 16 rows * 2ch * 40
        int r = it / 80, rem = it % 80;
        int ch = rem / 40, tt = rem % 40;
        float acc = cb1[ch];
#pragma unroll
        for (int k = 0; k < 25; ++k) acc += xs[r][tt + k] * cw1[ch * 25 + k];
        h1[r][ch * 40 + tt] = acc;
    }
    __syncthreads();

    int b = row0 >> 11, n0 = row0 & 2047;
    for (int it = t; it < 2048; it += 256) {      // 16 rows * 128 c (incl. zero pad)
        int r = it >> 7, c = it & 127;
        float val = 0.f;
        if (c < 124) {
            int co = c / 31, tt = c % 31;
            float acc = cb2[co];
#pragma unroll
            for (int ci = 0; ci < 2; ++ci)
#pragma unroll
                for (int k = 0; k < 10; ++k)
                    acc += h1[r][ci * 40 + tt + k] * cw2[(co * 2 + ci) * 10 + k];
            val = acc;
        }
        vt[((size_t)(b * 128 + c) << 11) + n0 + r] = (_Float16)val;
    }
}

// ---------------------------------------------------------------- fused attention
// Block: one (b,h), 64 q-rows; 4 waves, 16 rows each. Two passes over 32 key-tiles
// of 64. s computed via f16 hi/lo 3-MFMA split (fp32-accurate). No max-subtraction
// (|s| <= ~15, exp fits fp32).
// K (hi/lo) and V fragments are loaded DIRECTLY from global: per (b,h), K+V working
// set is ~1.5 MB shared across 32 row-blocks x 2 passes -> L1/L2-resident, and the
// B-fragment pattern (16 rows x 64B) is dense 64B segments per wave-load. No LDS
// staging, no per-tile barriers. LDS holds only the per-wave P-transpose buffer
// (same-wave RAW, lgkmcnt-ordered) and the epilogue O overlay.
// Pass1: l = sum exp(s). Pass2: attn = exp(s)/l written fp32 nontemporal;
// P -> f16 -> LDS -> A-frag; O += P.V via MFMA; epilogue projects O through W_out
// and atomicAdds into out.
__global__ __launch_bounds__(256, 4) void attn_kernel(
    const _Float16* __restrict__ qhi_g, const _Float16* __restrict__ qlo_g,
    const _Float16* __restrict__ khi_g, const _Float16* __restrict__ klo_g,
    const _Float16* __restrict__ vt_g, const float* __restrict__ Wout,
    float* __restrict__ outp, float* __restrict__ attn)
{
    // LDS: pbuf 4x[16][72] f16 (9216 B) during main loop; epilogue overlays
    // o_lds[64][132] fp32 (33792 B) on the whole buffer.
    __shared__ __align__(16) char smem[33792];

    int t = threadIdx.x;
    int w = t >> 6, lane = t & 63, quad = lane >> 4, m = lane & 15;
    _Float16* PB = (_Float16*)smem + w * 1152;   // per-wave [16][72]

    int ib = blockIdx.x;                       // XCD-grouping swizzle: 4 bh per xcd slot
    int bh = (ib & 7) * 4 + ((ib >> 3) & 3);
    int rowblk = ib >> 5;
    int b = bh >> 3, h = bh & 7;
    int row0 = rowblk * 64;

    // Q fragments (A-layout: row = lane&15, k = quad*8 + j), resident whole kernel
    const size_t qoff = ((size_t)(bh * 2048 + row0 + w * 16 + m)) << 6;
    half8 qh[2], ql[2];
    qh[0] = *(const half8*)(qhi_g + qoff + quad * 8);
    qh[1] = *(const half8*)(qhi_g + qoff + quad * 8 + 32);
    ql[0] = *(const half8*)(qlo_g + qoff + quad * 8);
    ql[1] = *(const half8*)(qlo_g + qoff + quad * 8 + 32);

    // K fragment bases: row = chunk*16 + m, elem = dh*32 + quad*8
    const size_t kbase = (((size_t)(bh * 2048)) << 6) + (size_t)m * 64 + quad * 8;
    const _Float16* kh_base = khi_g + kbase;
    const _Float16* kl_base = klo_g + kbase;

    // ---------------- pass 1: row sums of exp(s)
    float ls0 = 0.f, ls1 = 0.f, ls2 = 0.f, ls3 = 0.f;
    for (int tile = 0; tile < 32; ++tile) {
        const _Float16* kh = kh_base + tile * 4096;
        const _Float16* kl = kl_base + tile * 4096;
#pragma unroll
        for (int chunk = 0; chunk < 4; ++chunk) {
            f32x4 acc = {0.f, 0.f, 0.f, 0.f};
#pragma unroll
            for (int dh = 0; dh < 2; ++dh) {
                half8 bhv = *(const half8*)(kh + chunk * 1024 + dh * 32);
                half8 blv = *(const half8*)(kl + chunk * 1024 + dh * 32);
                acc = MFMA16(qh[dh], bhv, acc);
                acc = MFMA16(ql[dh], bhv, acc);
                acc = MFMA16(qh[dh], blv, acc);
            }
            ls0 += __expf(acc[0]); ls1 += __expf(acc[1]);
            ls2 += __expf(acc[2]); ls3 += __expf(acc[3]);
        }
    }
#pragma unroll
    for (int mask = 1; mask <= 8; mask <<= 1) {
        ls0 += __shfl_xor(ls0, mask);
        ls1 += __shfl_xor(ls1, mask);
        ls2 += __shfl_xor(ls2, mask);
        ls3 += __shfl_xor(ls3, mask);
    }
    float ri0 = 1.f / ls0, ri1 = 1.f / ls1, ri2 = 1.f / ls2, ri3 = 1.f / ls3;

    // ---------------- pass 2: attn write + P.V
    f32x4 oacc[8];
#pragma unroll
    for (int cc = 0; cc < 8; ++cc) oacc[cc] = (f32x4){0.f, 0.f, 0.f, 0.f};
    float* attn_b = attn + (((size_t)bh) << 22);
    // V fragment base: row c = cc*16 + m (stride 2048), elem = kk*32 + quad*8
    const _Float16* v_base = vt_g + (((size_t)(b * 128 + m)) << 11) + quad * 8;

    for (int tile = 0; tile < 32; ++tile) {
        const _Float16* kh = kh_base + tile * 4096;
        const _Float16* kl = kl_base + tile * 4096;
        int n0t = tile * 64;
#pragma unroll
        for (int chunk = 0; chunk < 4; ++chunk) {
            f32x4 acc = {0.f, 0.f, 0.f, 0.f};
#pragma unroll
            for (int dh = 0; dh < 2; ++dh) {
                half8 bhv = *(const half8*)(kh + chunk * 1024 + dh * 32);
                half8 blv = *(const half8*)(kl + chunk * 1024 + dh * 32);
                acc = MFMA16(qh[dh], bhv, acc);
                acc = MFMA16(ql[dh], bhv, acc);
                acc = MFMA16(qh[dh], blv, acc);
            }
            int col = n0t + chunk * 16 + m;
            int rg = row0 + w * 16 + quad * 4;
            float p0 = __expf(acc[0]) * ri0;
            float p1 = __expf(acc[1]) * ri1;
            float p2 = __expf(acc[2]) * ri2;
            float p3 = __expf(acc[3]) * ri3;
            __builtin_nontemporal_store(p0, attn_b + (size_t)(rg + 0) * 2048 + col);
            __builtin_nontemporal_store(p1, attn_b + (size_t)(rg + 1) * 2048 + col);
            __builtin_nontemporal_store(p2, attn_b + (size_t)(rg + 2) * 2048 + col);
            __builtin_nontemporal_store(p3, attn_b + (size_t)(rg + 3) * 2048 + col);
            PB[(quad * 4 + 0) * 72 + chunk * 16 + m] = (_Float16)p0;
            PB[(quad * 4 + 1) * 72 + chunk * 16 + m] = (_Float16)p1;
            PB[(quad * 4 + 2) * 72 + chunk * 16 + m] = (_Float16)p2;
            PB[(quad * 4 + 3) * 72 + chunk * 16 + m] = (_Float16)p3;
        }
        // P.V  (same-wave LDS RAW on PB; DS pipe is in-order, compiler inserts lgkmcnt)
#pragma unroll
        for (int kk = 0; kk < 2; ++kk) {
            half8 a = *(const half8*)(PB + m * 72 + kk * 32 + quad * 8);
#pragma unroll
            for (int cc = 0; cc < 8; ++cc) {
                half8 bv = *(const half8*)(v_base + ((size_t)cc << 15) + n0t + kk * 32);
                oacc[cc] = MFMA16(a, bv, oacc[cc]);
            }
        }
    }

    // ---------------- epilogue: project O (64x124) through W_out, atomicAdd into out
    __syncthreads();
    float* o_lds = (float*)smem;               // [64][132] fp32, overlays PB
#pragma unroll
    for (int cc = 0; cc < 8; ++cc)
#pragma unroll
        for (int r = 0; r < 4; ++r)
            o_lds[(w * 16 + quad * 4 + r) * 132 + cc * 16 + m] = oacc[cc][r];
    __syncthreads();

    int d = t & 63, rg2 = t >> 6;
    const float* wrow = Wout + d * 992 + h * 124;    // 16B-aligned (496 = 31*16)
    for (int rr = 0; rr < 16; ++rr) {
        int row = rg2 + rr * 4;
        const float* orow = o_lds + row * 132;
        float acc = 0.f;
#pragma unroll
        for (int c4 = 0; c4 < 31; ++c4) {
            float4 wv = ((const float4*)wrow)[c4];
            float4 ov = ((const float4*)orow)[c4];
            acc += ov.x * wv.x + ov.y * wv.y + ov.z * wv.z + ov.w * wv.w;
        }
        atomicAdd(outp + ((size_t)(b * 2048 + row0 + row) << 6) + d, acc);
    }
}

// ----------------------------------------------------------------
extern "C" void kernel_launch(void* const* d_in, const int* in_sizes, int n_in,
                              void* d_out, int out_size, void* d_ws, size_t ws_size,
                              hipStream_t stream) {
    const float* x    = (const float*)d_in[0];
    const float* Wqk  = (const float*)d_in[1];
    const float* w1   = (const float*)d_in[2];
    const float* b1   = (const float*)d_in[3];
    const float* w2   = (const float*)d_in[4];
    const float* b2   = (const float*)d_in[5];
    const float* Wout = (const float*)d_in[6];
    const float* bout = (const float*)d_in[7];

    float* out  = (float*)d_out;
    float* attn = out + 524288;                 // (4,8,2048,2048) follows (4,2048,64)

    _Float16* ws  = (_Float16*)d_ws;            // ~34 MB of f16 scratch
    _Float16* qhi = ws;
    _Float16* qlo = ws + 4194304;
    _Float16* khi = ws + 8388608;
    _Float16* klo = ws + 12582912;
    _Float16* vt  = ws + 16777216;              // (4,128,2048)

    init_out_kernel<<<2048, 256, 0, stream>>>(bout, out);
    qk_proj_kernel<<<512, 256, 0, stream>>>(x, Wqk, qhi, qlo, khi, klo);
    conv_v_kernel<<<512, 256, 0, stream>>>(x, w1, b1, w2, b2, vt);
    attn_kernel<<<1024, 256, 0, stream>>>(qhi, qlo, khi, klo, vt, Wout, out, attn);
}

// Round 2
// 782.910 us; speedup vs baseline: 1.5941x; 1.5941x over previous
//
#include <hip/hip_runtime.h>

typedef _Float16 half8 __attribute__((ext_vector_type(8)));
typedef float f32x4 __attribute__((ext_vector_type(4)));

#define MFMA16(a, b, c) __builtin_amdgcn_mfma_f32_16x16x32_f16(a, b, c, 0, 0, 0)

// ---------------------------------------------------------------- init out = b_out
__global__ void init_out_kernel(const float* __restrict__ bout, float* __restrict__ out) {
    int i = blockIdx.x * 256 + threadIdx.x;   // 524288 total
    out[i] = bout[i & 63];
}

// ---------------------------------------------------------------- qk projection
// qk = x @ W_qk.T ; q scaled by 0.125 ; split fp32 -> f16 hi + f16 lo.
// layouts: q_hi[b][h][n][d] etc. Each thread owns one output column o (W row in regs),
// iterates 64 x-rows staged in LDS (broadcast reads). 512 blocks -> 2 blocks/CU.
__global__ __launch_bounds__(256) void qk_proj_kernel(
    const float* __restrict__ x, const float* __restrict__ Wqk,
    _Float16* __restrict__ qhi, _Float16* __restrict__ qlo,
    _Float16* __restrict__ khi, _Float16* __restrict__ klo)
{
    __shared__ float4 xs[64][16];
    int t = threadIdx.x;
    int oc = blockIdx.x & 3;          // o-chunk: 4 * 256 = 1024 outputs
    int rowblk = blockIdx.x >> 2;     // 128 row-blocks of 64 rows
    int row0 = rowblk * 64;
    int o = oc * 256 + t;

    float4 wr[16];
    const float4* wp = (const float4*)(Wqk + o * 64);
#pragma unroll
    for (int j = 0; j < 16; ++j) wr[j] = wp[j];

    const float4* xsrc = (const float4*)(x + (size_t)row0 * 64);
#pragma unroll
    for (int i = 0; i < 4; ++i) {
        int idx = t + i * 256;        // 0..1023
        xs[idx >> 4][idx & 15] = xsrc[idx];
    }
    __syncthreads();

    bool isq = o < 512;
    int oo = isq ? o : o - 512;
    int h = oo >> 6, d = oo & 63;
    float scl = isq ? 0.125f : 1.0f;  // fold dots scale into q (exact, pow2)
    _Float16* hp = isq ? qhi : khi;
    _Float16* lp = isq ? qlo : klo;

    for (int r = 0; r < 64; ++r) {
        float acc = 0.f;
#pragma unroll
        for (int j = 0; j < 16; ++j) {
            float4 xv = xs[r][j];
            float4 wv = wr[j];
            acc += xv.x * wv.x + xv.y * wv.y + xv.z * wv.z + xv.w * wv.w;
        }
        float val = acc * scl;
        _Float16 hi = (_Float16)val;
        _Float16 lo = (_Float16)(val - (float)hi);
        int row = row0 + r;
        int b = row >> 11, n = row & 2047;
        size_t idx = ((size_t)((b * 8 + h) * 2048 + n) << 6) + d;
        hp[idx] = hi;
        lp[idx] = lo;
    }
}

// ---------------------------------------------------------------- conv value chain
// x(64) -> conv1(2ch,25tap) -> h1(2,40) -> conv2(4ch,2in,10tap) -> v(124), pad to 128.
// store transposed: vt[b][c][n]  (c-major rows of length 2048), f16.
__global__ __launch_bounds__(256) void conv_v_kernel(
    const float* __restrict__ x,
    const float* __restrict__ w1, const float* __restrict__ b1,
    const float* __restrict__ w2, const float* __restrict__ b2,
    _Float16* __restrict__ vt)
{
    __shared__ float xs[16][64];
    __shared__ float h1[16][80];          // [row][ci*40 + t]
    __shared__ float cw1[50], cb1[2], cw2[80], cb2[4];
    int t = threadIdx.x;
    int row0 = blockIdx.x * 16;

    ((float4*)&xs[0][0])[t] = ((const float4*)(x + (size_t)row0 * 64))[t];
    if (t < 50) cw1[t] = w1[t];
    else if (t < 52) cb1[t - 50] = b1[t - 50];
    else if (t < 132) cw2[t - 52] = w2[t - 52];
    else if (t < 136) cb2[t - 132] = b2[t - 132];
    __syncthreads();

    for (int it = t; it < 1280; it += 256) {      // 16 rows * 2ch * 40
        int r = it / 80, rem = it % 80;
        int ch = rem / 40, tt = rem % 40;
        float acc = cb1[ch];
#pragma unroll
        for (int k = 0; k < 25; ++k) acc += xs[r][tt + k] * cw1[ch * 25 + k];
        h1[r][ch * 40 + tt] = acc;
    }
    __syncthreads();

    int b = row0 >> 11, n0 = row0 & 2047;
    for (int it = t; it < 2048; it += 256) {      // 16 rows * 128 c (incl. zero pad)
        int r = it >> 7, c = it & 127;
        float val = 0.f;
        if (c < 124) {
            int co = c / 31, tt = c % 31;
            float acc = cb2[co];
#pragma unroll
            for (int ci = 0; ci < 2; ++ci)
#pragma unroll
                for (int k = 0; k < 10; ++k)
                    acc += h1[r][ci * 40 + tt + k] * cw2[(co * 2 + ci) * 10 + k];
            val = acc;
        }
        vt[((size_t)(b * 128 + c) << 11) + n0 + r] = (_Float16)val;
    }
}

// ---------------------------------------------------------------- fused attention
// Block: one (b,h), 128 q-rows; 4 waves, each owns TWO 16-row groups (g=0: rows
// row0+w*16.., g=1: rows row0+64+w*16..). Two passes over 32 key-tiles of 64.
// s via f16 hi/lo 3-MFMA split (fp32-accurate); no max-subtraction (|s| <= ~15).
// K/V staged in LDS per tile (proven latency-hiding structure); the 128-row block
// amortizes staging + barriers over 2x the MFMA work, and K fragments read from
// LDS feed BOTH row groups; V fragments are shared across groups in the PV loop
// (two per-wave P buffers). Pass1: l = sum exp(s). Pass2: attn = exp(s)/l written
// fp32 nontemporal; P -> f16 -> LDS -> A-frag; O += P.V via MFMA; epilogue projects
// O through W_out (two 64-row halves) and atomicAdds into out.
__global__ __launch_bounds__(256, 2) void attn_kernel(
    const _Float16* __restrict__ qhi_g, const _Float16* __restrict__ qlo_g,
    const _Float16* __restrict__ khi_g, const _Float16* __restrict__ klo_g,
    const _Float16* __restrict__ vt_g, const float* __restrict__ Wout,
    float* __restrict__ outp, float* __restrict__ attn)
{
    // LDS: khi[64][72] | klo[64][72] | vt[128][72] | pbuf 4 waves x 2 x [16][72]
    //  = 9216 + 9216 + 18432 + 18432 = 55296 B  (2 blocks/CU)
    // epilogue overlays o_lds[64][132] fp32 (33792 B).
    __shared__ __align__(16) char smem[55296];
    _Float16* KHI = (_Float16*)smem;
    _Float16* KLO = (_Float16*)(smem + 9216);
    _Float16* VT  = (_Float16*)(smem + 18432);

    int t = threadIdx.x;
    int w = t >> 6, lane = t & 63, quad = lane >> 4, m = lane & 15;
    _Float16* PB0 = (_Float16*)(smem + 36864) + w * 2304;   // group 0: [16][72]
    _Float16* PB1 = PB0 + 1152;                              // group 1: [16][72]

    int ib = blockIdx.x;                       // 512 blocks; XCD-grouping swizzle
    int bh = (ib & 7) * 4 + ((ib >> 3) & 3);
    int rowblk = ib >> 5;                      // 0..15, 128 rows each
    int b = bh >> 3, h = bh & 7;
    int row0 = rowblk * 128;

    // Q fragments for both row groups (A-layout: row = m, k = quad*8 + j)
    const size_t qoff0 = ((size_t)(bh * 2048 + row0 + w * 16 + m)) << 6;
    const size_t qoff1 = qoff0 + (size_t)(64 << 6);
    half8 qh0[2], ql0[2], qh1[2], ql1[2];
    qh0[0] = *(const half8*)(qhi_g + qoff0 + quad * 8);
    qh0[1] = *(const half8*)(qhi_g + qoff0 + quad * 8 + 32);
    ql0[0] = *(const half8*)(qlo_g + qoff0 + quad * 8);
    ql0[1] = *(const half8*)(qlo_g + qoff0 + quad * 8 + 32);
    qh1[0] = *(const half8*)(qhi_g + qoff1 + quad * 8);
    qh1[1] = *(const half8*)(qhi_g + qoff1 + quad * 8 + 32);
    ql1[0] = *(const half8*)(qlo_g + qoff1 + quad * 8);
    ql1[1] = *(const half8*)(qlo_g + qoff1 + quad * 8 + 32);

    const size_t kbase = ((size_t)(bh * 2048)) << 6;

    // ---------------- pass 1: row sums of exp(s) for both groups
    float ls[8];
#pragma unroll
    for (int i = 0; i < 8; ++i) ls[i] = 0.f;
    for (int tile = 0; tile < 32; ++tile) {
        __syncthreads();
        const _Float16* ks = khi_g + kbase + (size_t)tile * (64 * 64);
        const _Float16* lsrc = klo_g + kbase + (size_t)tile * (64 * 64);
#pragma unroll
        for (int rep = 0; rep < 2; ++rep) {
            int c = t + rep * 256;             // 0..511
            int key = c >> 3, seg = c & 7;
            *(half8*)(KHI + key * 72 + seg * 8) = *(const half8*)(ks + key * 64 + seg * 8);
            *(half8*)(KLO + key * 72 + seg * 8) = *(const half8*)(lsrc + key * 64 + seg * 8);
        }
        __syncthreads();
#pragma unroll
        for (int chunk = 0; chunk < 4; ++chunk) {
            f32x4 a0 = {0.f, 0.f, 0.f, 0.f};
            f32x4 a1 = {0.f, 0.f, 0.f, 0.f};
#pragma unroll
            for (int dh = 0; dh < 2; ++dh) {
                half8 bhv = *(const half8*)(KHI + (chunk * 16 + m) * 72 + dh * 32 + quad * 8);
                half8 blv = *(const half8*)(KLO + (chunk * 16 + m) * 72 + dh * 32 + quad * 8);
                a0 = MFMA16(qh0[dh], bhv, a0);
                a0 = MFMA16(ql0[dh], bhv, a0);
                a0 = MFMA16(qh0[dh], blv, a0);
                a1 = MFMA16(qh1[dh], bhv, a1);
                a1 = MFMA16(ql1[dh], bhv, a1);
                a1 = MFMA16(qh1[dh], blv, a1);
            }
            ls[0] += __expf(a0[0]); ls[1] += __expf(a0[1]);
            ls[2] += __expf(a0[2]); ls[3] += __expf(a0[3]);
            ls[4] += __expf(a1[0]); ls[5] += __expf(a1[1]);
            ls[6] += __expf(a1[2]); ls[7] += __expf(a1[3]);
        }
    }
#pragma unroll
    for (int mask = 1; mask <= 8; mask <<= 1) {
#pragma unroll
        for (int i = 0; i < 8; ++i) ls[i] += __shfl_xor(ls[i], mask);
    }
    float ri[8];
#pragma unroll
    for (int i = 0; i < 8; ++i) ri[i] = 1.f / ls[i];

    // ---------------- pass 2: attn write + P.V
    f32x4 oacc0[8], oacc1[8];
#pragma unroll
    for (int cc = 0; cc < 8; ++cc) {
        oacc0[cc] = (f32x4){0.f, 0.f, 0.f, 0.f};
        oacc1[cc] = (f32x4){0.f, 0.f, 0.f, 0.f};
    }
    float* attn_b = attn + (((size_t)bh) << 22);
    const _Float16* vs_base = vt_g + (((size_t)b * 128) << 11);

    for (int tile = 0; tile < 32; ++tile) {
        __syncthreads();
        const _Float16* ks = khi_g + kbase + (size_t)tile * (64 * 64);
        const _Float16* lsrc = klo_g + kbase + (size_t)tile * (64 * 64);
#pragma unroll
        for (int rep = 0; rep < 2; ++rep) {
            int c = t + rep * 256;
            int key = c >> 3, seg = c & 7;
            *(half8*)(KHI + key * 72 + seg * 8) = *(const half8*)(ks + key * 64 + seg * 8);
            *(half8*)(KLO + key * 72 + seg * 8) = *(const half8*)(lsrc + key * 64 + seg * 8);
        }
#pragma unroll
        for (int rep = 0; rep < 4; ++rep) {
            int c = t + rep * 256;             // 0..1023
            int ch = c >> 3, seg = c & 7;
            *(half8*)(VT + ch * 72 + seg * 8) =
                *(const half8*)(vs_base + (size_t)ch * 2048 + tile * 64 + seg * 8);
        }
        __syncthreads();

        int n0t = tile * 64;
#pragma unroll
        for (int chunk = 0; chunk < 4; ++chunk) {
            f32x4 a0 = {0.f, 0.f, 0.f, 0.f};
            f32x4 a1 = {0.f, 0.f, 0.f, 0.f};
#pragma unroll
            for (int dh = 0; dh < 2; ++dh) {
                half8 bhv = *(const half8*)(KHI + (chunk * 16 + m) * 72 + dh * 32 + quad * 8);
                half8 blv = *(const half8*)(KLO + (chunk * 16 + m) * 72 + dh * 32 + quad * 8);
                a0 = MFMA16(qh0[dh], bhv, a0);
                a0 = MFMA16(ql0[dh], bhv, a0);
                a0 = MFMA16(qh0[dh], blv, a0);
                a1 = MFMA16(qh1[dh], bhv, a1);
                a1 = MFMA16(ql1[dh], bhv, a1);
                a1 = MFMA16(qh1[dh], blv, a1);
            }
            int col = n0t + chunk * 16 + m;
            int rg0 = row0 + w * 16 + quad * 4;
            int rg1 = rg0 + 64;
            float p00 = __expf(a0[0]) * ri[0];
            float p01 = __expf(a0[1]) * ri[1];
            float p02 = __expf(a0[2]) * ri[2];
            float p03 = __expf(a0[3]) * ri[3];
            float p10 = __expf(a1[0]) * ri[4];
            float p11 = __expf(a1[1]) * ri[5];
            float p12 = __expf(a1[2]) * ri[6];
            float p13 = __expf(a1[3]) * ri[7];
            __builtin_nontemporal_store(p00, attn_b + (size_t)(rg0 + 0) * 2048 + col);
            __builtin_nontemporal_store(p01, attn_b + (size_t)(rg0 + 1) * 2048 + col);
            __builtin_nontemporal_store(p02, attn_b + (size_t)(rg0 + 2) * 2048 + col);
            __builtin_nontemporal_store(p03, attn_b + (size_t)(rg0 + 3) * 2048 + col);
            __builtin_nontemporal_store(p10, attn_b + (size_t)(rg1 + 0) * 2048 + col);
            __builtin_nontemporal_store(p11, attn_b + (size_t)(rg1 + 1) * 2048 + col);
            __builtin_nontemporal_store(p12, attn_b + (size_t)(rg1 + 2) * 2048 + col);
            __builtin_nontemporal_store(p13, attn_b + (size_t)(rg1 + 3) * 2048 + col);
            PB0[(quad * 4 + 0) * 72 + chunk * 16 + m] = (_Float16)p00;
            PB0[(quad * 4 + 1) * 72 + chunk * 16 + m] = (_Float16)p01;
            PB0[(quad * 4 + 2) * 72 + chunk * 16 + m] = (_Float16)p02;
            PB0[(quad * 4 + 3) * 72 + chunk * 16 + m] = (_Float16)p03;
            PB1[(quad * 4 + 0) * 72 + chunk * 16 + m] = (_Float16)p10;
            PB1[(quad * 4 + 1) * 72 + chunk * 16 + m] = (_Float16)p11;
            PB1[(quad * 4 + 2) * 72 + chunk * 16 + m] = (_Float16)p12;
            PB1[(quad * 4 + 3) * 72 + chunk * 16 + m] = (_Float16)p13;
        }
        // P.V for both groups; V fragment loaded once, used twice.
        // (same-wave LDS RAW on PB; DS pipe is in-order, compiler inserts lgkmcnt)
#pragma unroll
        for (int kk = 0; kk < 2; ++kk) {
            half8 a0 = *(const half8*)(PB0 + m * 72 + kk * 32 + quad * 8);
            half8 a1 = *(const half8*)(PB1 + m * 72 + kk * 32 + quad * 8);
#pragma unroll
            for (int cc = 0; cc < 8; ++cc) {
                half8 bv = *(const half8*)(VT + (cc * 16 + m) * 72 + kk * 32 + quad * 8);
                oacc0[cc] = MFMA16(a0, bv, oacc0[cc]);
                oacc1[cc] = MFMA16(a1, bv, oacc1[cc]);
            }
        }
    }

    // ---------------- epilogue: project O (two 64x124 halves) through W_out
    float* o_lds = (float*)smem;               // [64][132] fp32, overlays everything
    int d = t & 63, rg2 = t >> 6;
    const float* wrow = Wout + d * 992 + h * 124;    // 16B-aligned (496 = 31*16)
#pragma unroll
    for (int g = 0; g < 2; ++g) {
        __syncthreads();
#pragma unroll
        for (int cc = 0; cc < 8; ++cc)
#pragma unroll
            for (int r = 0; r < 4; ++r)
                o_lds[(w * 16 + quad * 4 + r) * 132 + cc * 16 + m] =
                    g ? oacc1[cc][r] : oacc0[cc][r];
        __syncthreads();

        for (int rr = 0; rr < 16; ++rr) {
            int row = rg2 + rr * 4;
            const float* orow = o_lds + row * 132;
            float acc = 0.f;
#pragma unroll
            for (int c4 = 0; c4 < 31; ++c4) {
                float4 wv = ((const float4*)wrow)[c4];
                float4 ov = ((const float4*)orow)[c4];
                acc += ov.x * wv.x + ov.y * wv.y + ov.z * wv.z + ov.w * wv.w;
            }
            atomicAdd(outp + ((size_t)(b * 2048 + row0 + g * 64 + row) << 6) + d, acc);
        }
    }
}

// ----------------------------------------------------------------
extern "C" void kernel_launch(void* const* d_in, const int* in_sizes, int n_in,
                              void* d_out, int out_size, void* d_ws, size_t ws_size,
                              hipStream_t stream) {
    const float* x    = (const float*)d_in[0];
    const float* Wqk  = (const float*)d_in[1];
    const float* w1   = (const float*)d_in[2];
    const float* b1   = (const float*)d_in[3];
    const float* w2   = (const float*)d_in[4];
    const float* b2   = (const float*)d_in[5];
    const float* Wout = (const float*)d_in[6];
    const float* bout = (const float*)d_in[7];

    float* out  = (float*)d_out;
    float* attn = out + 524288;                 // (4,8,2048,2048) follows (4,2048,64)

    _Float16* ws  = (_Float16*)d_ws;            // ~34 MB of f16 scratch
    _Float16* qhi = ws;
    _Float16* qlo = ws + 4194304;
    _Float16* khi = ws + 8388608;
    _Float16* klo = ws + 12582912;
    _Float16* vt  = ws + 16777216;              // (4,128,2048)

    init_out_kernel<<<2048, 256, 0, stream>>>(bout, out);
    qk_proj_kernel<<<512, 256, 0, stream>>>(x, Wqk, qhi, qlo, khi, klo);
    conv_v_kernel<<<512, 256, 0, stream>>>(x, w1, b1, w2, b2, vt);
    attn_kernel<<<512, 256, 0, stream>>>(qhi, qlo, khi, klo, vt, Wout, out, attn);
}